// Round 1
// 812.721 us; speedup vs baseline: 1.0021x; 1.0021x over previous
//
#include <hip/hip_runtime.h>
#include <cstdint>
#include <cstddef>

// ---------------------------------------------------------------------------
// WindowAttention: B=1024 windows, N=216 tokens, H=6 heads, D=32, C=192.
// K0 prep (weights->bf16, bias expand, x->bf16 into out-region upper halves) ->
// K1 fused qkv+attention (bf16 MFMA, no-max softmax, hoisted bias, two-pass
// softmax/PV) -> K2 proj GEMM in-place on d_out.
//
// This round: occupancy attack. attn LDS 158KB -> 68.6KB (x read from global
// bf16 scratch instead of LDS) and proj LDS 163KB -> 76.8KB (A-frags read
// directly from global attnb) so BOTH kernels fit 2 blocks/CU (32 waves/CU);
// the two resident blocks run phases out of lockstep and hide barrier drains
// and L1/L2 load latency. __launch_bounds__(1024,8) pins VGPR<=64.
//
// k-order permutation trick: MFMA dot products are invariant under a shared
// permutation of the K dimension. We interleave q/k d-columns (col'=2*(d&15)
// +(d>>4)) and P/vT m-columns identically, so C-layout pairs (t=0,t=1) land
// in adjacent shorts -> aligned b32 LDS writes instead of scalar b16.
// ---------------------------------------------------------------------------

typedef __attribute__((ext_vector_type(8))) short short8;   // 8 x bf16 frag
typedef __attribute__((ext_vector_type(4))) float f32x4;    // MFMA C/D
typedef unsigned short u16;
typedef unsigned int   u32;

#define SCALE_F 0.17677669529663687f  /* 32^-0.5 */

// LDS layout (attn): all byte offsets 16B-aligned
#define QS_OFF   0        // [224][40]  u16 = 17920 (rows 216..223 zeroed)
#define KS_OFF   17920    // [224][40]  u16 = 17920 (rows 216..223 zeroed)
#define VT_OFF   35840    // [32][232]  u16 = 14848 (perm cols; m-pads zeroed)
#define PCH_OFF  50688    // 14 waves x [16][40] u16 = 17920
#define ATTN_LDS 68608    // <= 81920 -> 2 blocks/CU

#define PROJ_LDS 76800    // [192][200] u16 weights only -> 2 blocks/CU

__device__ __forceinline__ u16 f2bf(float f) {
  union { float f; u32 u; } v; v.f = f;
  return (u16)((v.u + 0x7fffu + ((v.u >> 16) & 1u)) >> 16);  // RNE
}

__device__ __forceinline__ f32x4 mfma16(short8 a, short8 b, f32x4 c) {
  return __builtin_amdgcn_mfma_f32_16x16x32_bf16(a, b, c, 0, 0, 0);
}

// ---------------------------------------------------------------------------
// K0: x->bf16 (upper half of each block's out region), qkv_w->bf16,
// proj_w->bf16, bias expand to [h][c][l][n:224][t:2] bf16.
// m = c*32 + t*16 + l. m>=216 -> -inf bf16 (0xFF80) so exp()->0. n>=216 -> 0.
// ---------------------------------------------------------------------------
__global__ void prep_kernel(const float* __restrict__ x,
                            const float* __restrict__ qkv_w,
                            const float* __restrict__ proj_w,
                            const float* __restrict__ bias_table,
                            u16* __restrict__ wb,
                            u16* __restrict__ pwb,
                            u16* __restrict__ biasp,
                            float* outbuf) {
  const int tid = blockIdx.x * blockDim.x + threadIdx.x;
  const int stride = gridDim.x * blockDim.x;
  // x -> bf16 scratch: block b's slice goes to bytes [82944, 165888) of its
  // own out region (lower half is the bf16 attn-output scratch).
  const float4* x4 = (const float4*)x;
  for (int i = tid; i < 1024 * 10368; i += stride) {
    const int b = i / 10368, r = i % 10368;
    const float4 v = x4[i];
    union { u16 s[4]; unsigned long long u; } pk;
    pk.s[0] = f2bf(v.x); pk.s[1] = f2bf(v.y);
    pk.s[2] = f2bf(v.z); pk.s[3] = f2bf(v.w);
    *(unsigned long long*)((u16*)(outbuf + (size_t)b * 41472) + 41472 + r * 4) = pk.u;
  }
  for (int i = tid; i < 576 * 192; i += stride) wb[i] = f2bf(qkv_w[i]);
  for (int i = tid; i < 192 * 192; i += stride) pwb[i] = f2bf(proj_w[i]);
  for (int i = tid; i < 6 * 7 * 16 * 224 * 2; i += stride) {
    const int t = i & 1;
    int j = i >> 1;
    const int n = j % 224; j /= 224;
    const int l = j & 15;  j >>= 4;
    const int c = j % 7;
    const int h = j / 7;
    const int m = c * 32 + t * 16 + l;
    u16 val;
    if (n >= 216)      val = 0;        // pad rows: finite, discarded
    else if (m >= 216) val = 0xFF80;   // -inf bf16 -> exp = 0
    else {
      const int di = n / 36 - m / 36;
      const int dj = (n / 6) % 6 - (m / 6) % 6;
      const int dk = n % 6 - m % 6;
      const int idx = (di + 5) * 17 + (dj + 5) * 11 + (dk + 5);
      val = f2bf(bias_table[idx * 6 + h]);
    }
    biasp[i] = val;
  }
}

// ---------------------------------------------------------------------------
// K1: per-window fused qkv + attention. 2 blocks/CU.
// ---------------------------------------------------------------------------
__global__ __launch_bounds__(1024, 8)
void attn_kernel(const u16* __restrict__ wb, const u16* __restrict__ biasp,
                 float* outbuf) {
  extern __shared__ char smem[];
  u16* qs  = (u16*)(smem + QS_OFF);
  u16* ks  = (u16*)(smem + KS_OFF);
  u16* vT  = (u16*)(smem + VT_OFF);
  u16* pch = (u16*)(smem + PCH_OFF);

  const int b = blockIdx.x;
  const int tid = threadIdx.x;
  const int wave = tid >> 6;
  const int lane = tid & 63;
  const int quad = lane >> 4;
  const int lcol = lane & 15;

  const u16* xb   = (const u16*)(outbuf + (size_t)b * 41472) + 41472;  // [216][192]
  u16*       attnb = (u16*)(outbuf + (size_t)b * 41472);               // bf16 scratch

  // ---- zero the n-pad rows of qs/ks and the vT m-pad columns ----
  for (int i = tid; i < 8 * 40; i += 1024) { qs[216 * 40 + i] = 0; ks[216 * 40 + i] = 0; }
  // vT: m=216..223 -> perm cols 209,211,...,223 (odd), all 32 d-rows
  for (int i = tid; i < 32 * 8; i += 1024) {
    const int d = i >> 3, jj = i & 7;
    vT[d * 232 + 209 + 2 * jj] = 0;
  }
  __syncthreads();

  for (int h = 0; h < 6; ++h) {
    // ---------- Phase 1: q,k,v = x @ W_h^T ; 14 units (one 16-row tile each) ----
    for (int u = wave; u < 14; u += 16) {
      f32x4 acc[6] = {};
      const int ar0 = u * 16 + lcol;
      const int ar  = ar0 < 216 ? ar0 : 215;   // clamp: pad rows masked at write
#pragma unroll
      for (int kk = 0; kk < 6; ++kk) {
        const short8 a = *(const short8*)(xb + ar * 192 + kk * 32 + quad * 8);
#pragma unroll
        for (int j = 0; j < 6; ++j) {    // 0,1=q(lo,hi) 2,3=k 4,5=v
          const int fbase = (j >> 1) * 192 + h * 32 + (j & 1) * 16;
          const short8 bf = *(const short8*)(wb + (fbase + lcol) * 192 + kk * 32 + quad * 8);
          acc[j] = mfma16(a, bf, acc[j]);
        }
      }
      const int nb = u * 16 + quad * 4;
#pragma unroll
      for (int r = 0; r < 4; ++r) {
        const int n = nb + r;
        if (n < 216) {
          // q/k: interleaved d-cols -> (j,j+1) pair = adjacent shorts = b32
          *(u32*)(qs + n * 40 + 2 * lcol) =
              (u32)f2bf(acc[0][r]) | ((u32)f2bf(acc[1][r]) << 16);
          *(u32*)(ks + n * 40 + 2 * lcol) =
              (u32)f2bf(acc[2][r]) | ((u32)f2bf(acc[3][r]) << 16);
          const int pm = (n & ~31) | (2 * (n & 15)) | ((n >> 4) & 1);  // perm m
          vT[lcol * 232 + pm]        = f2bf(acc[4][r]);
          vT[(16 + lcol) * 232 + pm] = f2bf(acc[5][r]);
        }
      }
    }
    __syncthreads();

    // ---------- Phase 2: two-pass softmax(S)+PV per 16-row strip ----------
    if (wave < 14) {
      const int s = wave;
      u16* pw_ = pch + wave * 640;  // [16][40]

      // hoisted bias: 7 x uint4, each = 4 n-rows x (t0,t1) bf16 pairs
      uint4 bias_q[7];
#pragma unroll
      for (int c = 0; c < 7; ++c)
        bias_q[c] = *(const uint4*)(biasp + ((size_t)((h * 7 + c) * 16 + lcol)) * 448
                                    + (s * 16 + quad * 4) * 2);
      const short8 qa = *(const short8*)(qs + (s * 16 + lcol) * 40 + quad * 8);

      // pass 1: S = q.k^T, p = exp(S*scale + bias) packed to bf16 in regs
      u32 pP[7][4];
      f32x4 rsum = {};
#pragma unroll
      for (int c = 0; c < 7; ++c) {
        const short8 kb0 = *(const short8*)(ks + (c * 32 + lcol) * 40 + quad * 8);
        const short8 kb1 = *(const short8*)(ks + (c * 32 + 16 + lcol) * 40 + quad * 8);
        const f32x4 z = {};
        const f32x4 s0 = mfma16(qa, kb0, z);
        const f32x4 s1 = mfma16(qa, kb1, z);
        const u32* bw = (const u32*)&bias_q[c];
#pragma unroll
        for (int r = 0; r < 4; ++r) {
          union { u32 u; float f; } b0, b1;
          b0.u = bw[r] << 16;            // t=0 bias (low short)
          b1.u = bw[r] & 0xFFFF0000u;    // t=1 bias (high short)
          const float p0 = __expf(__builtin_fmaf(s0[r], SCALE_F, b0.f));
          const float p1 = __expf(__builtin_fmaf(s1[r], SCALE_F, b1.f));
          rsum[r] += p0 + p1;
          pP[c][r] = (u32)f2bf(p0) | ((u32)f2bf(p1) << 16);  // perm col pair
        }
      }

      // pass 2: LDS C->A transform + PV (short-latency chain only)
      f32x4 o0 = {}, o1 = {};
#pragma unroll
      for (int c = 0; c < 7; ++c) {
#pragma unroll
        for (int r = 0; r < 4; ++r)
          *(u32*)(pw_ + (quad * 4 + r) * 40 + 2 * lcol) = pP[c][r];
        __builtin_amdgcn_s_waitcnt(0);   // drain writes before same-wave read
        const short8 pa  = *(const short8*)(pw_ + lcol * 40 + quad * 8);
        const short8 vb0 = *(const short8*)(vT + lcol * 232 + c * 32 + quad * 8);
        const short8 vb1 = *(const short8*)(vT + (16 + lcol) * 232 + c * 32 + quad * 8);
        o0 = mfma16(pa, vb0, o0);
        o1 = mfma16(pa, vb1, o1);
      }

      // rowsum over the 16 lcol lanes of each quad, then scale + store
      f32x4 inv;
#pragma unroll
      for (int r = 0; r < 4; ++r) {
        float ssum = rsum[r];
        ssum += __shfl_xor(ssum, 1, 16);
        ssum += __shfl_xor(ssum, 2, 16);
        ssum += __shfl_xor(ssum, 4, 16);
        ssum += __shfl_xor(ssum, 8, 16);
        inv[r] = 1.0f / ssum;
      }
#pragma unroll
      for (int r = 0; r < 4; ++r) {
        const int n = s * 16 + quad * 4 + r;
        if (n < 216) {
          attnb[n * 192 + h * 32 + lcol]      = f2bf(o0[r] * inv[r]);
          attnb[n * 192 + h * 32 + 16 + lcol] = f2bf(o1[r] * inv[r]);
        }
      }
    }
    __syncthreads();
  }
}

// ---------------------------------------------------------------------------
// K2: out = attn @ proj_w^T + proj_b, block-local in-place on d_out.
// proj_w staged in LDS (padded stride 200); A-fragments loaded from GLOBAL
// attnb into registers BEFORE the barrier (the barrier then orders the
// in-place fp32 writes after all bf16 reads of the aliasing region).
// ---------------------------------------------------------------------------
__global__ __launch_bounds__(1024, 8)
void proj_kernel(const u16* __restrict__ pwb, const float* __restrict__ proj_b,
                 float* outbuf) {
  extern __shared__ char smem[];
  u16* pws = (u16*)smem;   // [192][200]
  const int b = blockIdx.x, tid = threadIdx.x;
  const int wave = tid >> 6, lane = tid & 63, quad = lane >> 4, lcol = lane & 15;
  float* myout = outbuf + (size_t)b * 41472;
  const u16* attnb = (const u16*)myout;

  for (int i = tid; i < 192 * 24; i += 1024) {
    const int row = i / 24, c8 = i % 24;
    *(short8*)(pws + row * 200 + c8 * 8) = *(const short8*)(pwb + row * 192 + c8 * 8);
  }

  // A-fragments: each wave owns one 16-row strip; every attnb element is read
  // by exactly one lane, so LDS staging was pure overhead. Loads must complete
  // before any wave's in-place writes -> issue here, barrier below.
  short8 a[6] = {};
  const bool active = wave < 14;
  if (active) {
    const int arow = wave * 16 + lcol;
    if (arow < 216) {
#pragma unroll
      for (int kk = 0; kk < 6; ++kk)
        a[kk] = *(const short8*)(attnb + arow * 192 + kk * 32 + quad * 8);
    }
  }
  __syncthreads();

  if (active) {
    for (int nt = 0; nt < 12; ++nt) {
      f32x4 acc = {};
#pragma unroll
      for (int kk = 0; kk < 6; ++kk) {
        const short8 bf = *(const short8*)(pws + (nt * 16 + lcol) * 200 + kk * 32 + quad * 8);
        acc = mfma16(a[kk], bf, acc);
      }
      const float pbv = proj_b[nt * 16 + lcol];
      const int nb = wave * 16 + quad * 4;
#pragma unroll
      for (int r = 0; r < 4; ++r) {
        const int n = nb + r;
        if (n < 216) myout[n * 192 + nt * 16 + lcol] = acc[r] + pbv;
      }
    }
  }
}

// ---------------------------------------------------------------------------
extern "C" void kernel_launch(void* const* d_in, const int* in_sizes, int n_in,
                              void* d_out, int out_size, void* d_ws, size_t ws_size,
                              hipStream_t stream) {
  (void)in_sizes; (void)n_in; (void)out_size; (void)ws_size;
  const float* x          = (const float*)d_in[0];
  const float* qkv_w      = (const float*)d_in[1];
  const float* proj_w     = (const float*)d_in[2];
  const float* proj_b     = (const float*)d_in[3];
  const float* bias_table = (const float*)d_in[4];
  float* out = (float*)d_out;

  u16* wb    = (u16*)d_ws;                              // 221184 B
  u16* pwb   = (u16*)((char*)d_ws + 221184);            //  73728 B
  u16* biasp = (u16*)((char*)d_ws + 294912);            // 602112 B

  (void)hipFuncSetAttribute((const void*)attn_kernel,
                            hipFuncAttributeMaxDynamicSharedMemorySize, ATTN_LDS);
  (void)hipFuncSetAttribute((const void*)proj_kernel,
                            hipFuncAttributeMaxDynamicSharedMemorySize, PROJ_LDS);

  prep_kernel<<<dim3(1024), dim3(256), 0, stream>>>(x, qkv_w, proj_w, bias_table,
                                                    wb, pwb, biasp, out);
  attn_kernel<<<dim3(1024), dim3(1024), ATTN_LDS, stream>>>(wb, biasp, out);
  proj_kernel<<<dim3(1024), dim3(1024), PROJ_LDS, stream>>>(pwb, proj_b, out);
}